// Round 2
// 387.891 us; speedup vs baseline: 1.0730x; 1.0730x over previous
//
#include <hip/hip_runtime.h>
#include <cstdint>

#define RES    28
#define RES2   14
#define NHEAD  8
#define KDIM   16
#define DV     64
#define DHID   512
#define NSEQ   784
#define N2SEQ  196
#define BATCH  64
#define CIN    384

typedef unsigned short u16;
typedef short  short8_t __attribute__((ext_vector_type(8)));
typedef float  f32x4  __attribute__((ext_vector_type(4)));
typedef u16    us4    __attribute__((ext_vector_type(4)));
typedef u16    us8    __attribute__((ext_vector_type(8)));

__device__ __forceinline__ u16 f2bf(float f) {
    uint32_t u = __float_as_uint(f);
    return (u16)((u + 0x7fffu + ((u >> 16) & 1u)) >> 16);   // RNE
}
__device__ __forceinline__ float bf2f(u16 h) {
    return __uint_as_float(((uint32_t)h) << 16);
}

// ---------------------------------------------------------------------------
// One prep kernel: all weight transposes->bf16 + concatenated epilogue vecs.
// kvwt[640][384] = [k_w^T | v_w^T]; qwt[128][384]; pwt[768][512];
// kv_eps[1920] = [k_b|v_b, k_bn_s|v_bn_s, k_bn_b|v_bn_b]; qsb[256] = 0.25*[s|b]
// ---------------------------------------------------------------------------
#define PREP_N (49152 + 196608 + 49152 + 393216 + 1920 + 256)
__global__ __launch_bounds__(256)
void prep_kernel(const float* __restrict__ k_w, const float* __restrict__ v_w,
                 const float* __restrict__ q_proj_w, const float* __restrict__ proj_w,
                 const float* __restrict__ k_b, const float* __restrict__ v_b,
                 const float* __restrict__ k_bn_s, const float* __restrict__ v_bn_s,
                 const float* __restrict__ k_bn_b, const float* __restrict__ v_bn_b,
                 const float* __restrict__ q_bn_s, const float* __restrict__ q_bn_b,
                 u16* __restrict__ kvwt, u16* __restrict__ qwt, u16* __restrict__ pwt,
                 float* __restrict__ kv_eps, float* __restrict__ qsb)
{
    int i = blockIdx.x * 256 + threadIdx.x;
    if (i >= PREP_N) return;
    if (i < 49152) {                       // k_w^T -> kvwt rows 0..127
        int n = i / 384, k = i % 384;
        kvwt[i] = f2bf(k_w[(size_t)k * 128 + n]);
        return;
    }
    i -= 49152;
    if (i < 196608) {                      // v_w^T -> kvwt rows 128..639
        int n = i / 384, k = i % 384;
        kvwt[49152 + i] = f2bf(v_w[(size_t)k * 512 + n]);
        return;
    }
    i -= 196608;
    if (i < 49152) {                       // q_proj_w^T
        int n = i / 384, k = i % 384;
        qwt[i] = f2bf(q_proj_w[(size_t)k * 128 + n]);
        return;
    }
    i -= 49152;
    if (i < 393216) {                      // proj_w^T
        int n = i / 512, k = i % 512;
        pwt[i] = f2bf(proj_w[(size_t)k * 768 + n]);
        return;
    }
    i -= 393216;
    if (i < 1920) {                        // concatenated kv epilogue vectors
        int which = i / 640, j = i % 640;
        const float* a = which == 0 ? (j < 128 ? k_b : v_b)
                       : which == 1 ? (j < 128 ? k_bn_s : v_bn_s)
                                    : (j < 128 ? k_bn_b : v_bn_b);
        kv_eps[i] = a[j < 128 ? j : j - 128];
        return;
    }
    i -= 1920;
    qsb[i] = 0.25f * (i < 128 ? q_bn_s[i] : q_bn_b[i - 128]);
}

// ---------------------------------------------------------------------------
// biasC: attention bias pre-arranged in MFMA C-fragment layout
// idx = (((h*13+ti)*4+ks)*13+qt)*64 + lane, f32x4 over r.
// key = ti*64+ks*16+quad*4+r, q = qt*16+col; invalid key/q -> -1e30 (mask).
// ---------------------------------------------------------------------------
__global__ __launch_bounds__(256)
void biasC_kernel(const float* __restrict__ bias, float* __restrict__ biasC)
{
    int tid = blockIdx.x * 256 + threadIdx.x;
    if (tid >= NHEAD * 13 * 4 * 13 * 64) return;
    int lane = tid & 63;
    int rem  = tid >> 6;
    int qt = rem % 13; rem /= 13;
    int ks = rem % 4;  rem /= 4;
    int ti = rem % 13;
    int h  = rem / 13;
    int col = lane & 15, quad = lane >> 4;
    int q = qt * 16 + col;
    float4 out;
    float* po = &out.x;
    #pragma unroll
    for (int r = 0; r < 4; ++r) {
        int key = ti * 64 + ks * 16 + quad * 4 + r;
        float v;
        if (key >= NSEQ || q >= N2SEQ) {
            v = -1e30f;
        } else {
            int pi = q / 14, pj = q % 14;
            int ku = key / 28, kw = key % 28;
            int d0 = 2 * pj - kw; if (d0 < 0) d0 = -d0;
            int d1 = 2 * pi - ku; if (d1 < 0) d1 = -d1;
            v = bias[h * NSEQ + d0 * 28 + d1];
        }
        po[r] = v;
    }
    ((float4*)biasC)[tid] = out;
}

// ---------------------------------------------------------------------------
// MFMA GEMM: out = epi(A[M,K] @ Bt[N,K]^T)
// A_FP32: A is fp32, converted to bf16 during LDS staging (kills cast pass).
// OUT_MODE: 0 fp32 flat; 1 bf16 flat; 2 bf16 head-split (rpb rows/batch);
//           3 fused kv: bn<128 -> head-split k into outp (rpb=NSEQ),
//                       bn>=128 -> bf16 flat [row][512] into out2 at col-128.
// ---------------------------------------------------------------------------
#define TM 128
#define TN 128
#define TK 32

template<int OUT_MODE, int A_FP32>
__global__ __launch_bounds__(256)
void gemm_mfma_kernel(const void* __restrict__ Av, const u16* __restrict__ Bt,
                      const float* __restrict__ bias, const float* __restrict__ scale,
                      const float* __restrict__ shift, void* __restrict__ outp,
                      u16* __restrict__ out2, int M, int N, int K, int rpb)
{
    __shared__ u16 As[TM * TK];
    __shared__ u16 Bs[TN * TK];

    const int t  = threadIdx.x;
    const int w  = t >> 6;
    const int li = t & 63;
    const int wm = w >> 1, wn = w & 1;
    const int bm = blockIdx.x * TM;
    const int bn = blockIdx.y * TN;
    const int m16 = li & 15;
    const int kg  = li >> 4;

    f32x4 acc[4][4];
    #pragma unroll
    for (int i = 0; i < 4; ++i)
        #pragma unroll
        for (int j = 0; j < 4; ++j) acc[i][j] = (f32x4)0.0f;

    for (int k0 = 0; k0 < K; k0 += TK) {
        #pragma unroll
        for (int i = 0; i < 2; ++i) {
            int c   = (w * 2 + i) * 64 + li;
            int row = c >> 2, kc = c & 3;
            if (A_FP32) {
                const float* ag = (const float*)Av + (size_t)(bm + row) * K + k0 + kc * 8;
                float4 a0 = *(const float4*)ag;
                float4 a1 = *(const float4*)(ag + 4);
                us8 vv;
                vv[0] = f2bf(a0.x); vv[1] = f2bf(a0.y); vv[2] = f2bf(a0.z); vv[3] = f2bf(a0.w);
                vv[4] = f2bf(a1.x); vv[5] = f2bf(a1.y); vv[6] = f2bf(a1.z); vv[7] = f2bf(a1.w);
                *(us8*)&As[(size_t)row * TK + kc * 8] = vv;
            } else {
                const u16* ag = (const u16*)Av + (size_t)(bm + row) * K + k0 + kc * 8;
                char* la = (char*)As + (size_t)(w * 2 + i) * 64 * 16;
                __builtin_amdgcn_global_load_lds(
                    (const __attribute__((address_space(1))) void*)ag,
                    (__attribute__((address_space(3))) void*)la, 16, 0, 0);
            }
            const u16* bg = Bt + (size_t)(bn + row) * K + k0 + kc * 8;
            char* lb = (char*)Bs + (size_t)(w * 2 + i) * 64 * 16;
            __builtin_amdgcn_global_load_lds(
                (const __attribute__((address_space(1))) void*)bg,
                (__attribute__((address_space(3))) void*)lb, 16, 0, 0);
        }
        __syncthreads();

        short8_t af[4], bf[4];
        #pragma unroll
        for (int mi = 0; mi < 4; ++mi)
            af[mi] = *(const short8_t*)&As[(wm * 64 + mi * 16 + m16) * TK + kg * 8];
        #pragma unroll
        for (int ni = 0; ni < 4; ++ni)
            bf[ni] = *(const short8_t*)&Bs[(wn * 64 + ni * 16 + m16) * TK + kg * 8];

        #pragma unroll
        for (int mi = 0; mi < 4; ++mi)
            #pragma unroll
            for (int ni = 0; ni < 4; ++ni)
                acc[mi][ni] = __builtin_amdgcn_mfma_f32_16x16x32_bf16(
                    af[mi], bf[ni], acc[mi][ni], 0, 0, 0);
        __syncthreads();
    }

    #pragma unroll
    for (int ni = 0; ni < 4; ++ni) {
        const int col = bn + wn * 64 + ni * 16 + m16;
        const float bi = bias[col], sc = scale[col], sh = shift[col];
        #pragma unroll
        for (int mi = 0; mi < 4; ++mi) {
            const int rbase = bm + wm * 64 + mi * 16 + kg * 4;
            #pragma unroll
            for (int r = 0; r < 4; ++r) {
                float val = (acc[mi][ni][r] + bi) * sc + sh;
                const int row = rbase + r;
                if (OUT_MODE == 0) {
                    ((float*)outp)[(size_t)row * N + col] = val;
                } else if (OUT_MODE == 1) {
                    ((u16*)outp)[(size_t)row * N + col] = f2bf(val);
                } else if (OUT_MODE == 2) {
                    int bb = row / rpb, tok = row % rpb;
                    int hh = col >> 4;
                    ((u16*)outp)[((size_t)(bb * NHEAD + hh) * rpb + tok) * 16 + (col & 15)] = f2bf(val);
                } else {   // fused kv
                    if (bn < 128) {
                        int bb = row / NSEQ, tok = row % NSEQ;
                        int hh = col >> 4;
                        ((u16*)outp)[((size_t)(bb * NHEAD + hh) * NSEQ + tok) * 16 + (col & 15)] = f2bf(val);
                    } else {
                        out2[(size_t)row * DHID + (col - 128)] = f2bf(val);
                    }
                }
            }
        }
    }
}

// ---------------------------------------------------------------------------
// q_in = dwconv3x3_s2_SAME(x) + q_local_b + x[::2,::2]   (fp32 in, bf16 out)
// ---------------------------------------------------------------------------
__global__ __launch_bounds__(256)
void qin_kernel(const float* __restrict__ x, const float* __restrict__ w,
                const float* __restrict__ b, u16* __restrict__ qin)
{
    const int C4 = CIN / 4;
    int idx = blockIdx.x * 256 + threadIdx.x;
    if (idx >= BATCH * RES2 * RES2 * C4) return;
    int c4 = idx % C4;
    int r  = idx / C4;
    int j  = r % RES2; r /= RES2;
    int i  = r % RES2;
    int bb = r / RES2;

    const float4* x4 = (const float4*)x;
    const float4* w4 = (const float4*)w;
    float4 acc = make_float4(0.f, 0.f, 0.f, 0.f);
    #pragma unroll
    for (int dy = 0; dy < 3; ++dy) {
        int iy = 2 * i + dy;
        if (iy >= RES) continue;
        #pragma unroll
        for (int dx = 0; dx < 3; ++dx) {
            int ix = 2 * j + dx;
            if (ix >= RES) continue;
            float4 xv = x4[((size_t)(bb * RES + iy) * RES + ix) * C4 + c4];
            float4 wv = w4[(dy * 3 + dx) * C4 + c4];
            acc.x += xv.x * wv.x; acc.y += xv.y * wv.y;
            acc.z += xv.z * wv.z; acc.w += xv.w * wv.w;
        }
    }
    float4 bv = ((const float4*)b)[c4];
    float4 xs = x4[((size_t)(bb * RES + 2 * i) * RES + 2 * j) * C4 + c4];
    us4 o;
    o.x = f2bf(acc.x + bv.x + xs.x);
    o.y = f2bf(acc.y + bv.y + xs.y);
    o.z = f2bf(acc.z + bv.z + xs.z);
    o.w = f2bf(acc.w + bv.w + xs.w);
    ((us4*)qin)[idx] = o;
}

// ---------------------------------------------------------------------------
// v_local = BN(dwconv3x3_s2(v)) : v bf16 in, bf16 out (attention RMWs this)
// ---------------------------------------------------------------------------
__global__ __launch_bounds__(256)
void vloc_kernel(const u16* __restrict__ v, const float* __restrict__ w,
                 const float* __restrict__ b, const float* __restrict__ s,
                 const float* __restrict__ sh, u16* __restrict__ out)
{
    const int C4 = DHID / 4;
    int idx = blockIdx.x * 256 + threadIdx.x;
    if (idx >= BATCH * RES2 * RES2 * C4) return;
    int c4 = idx % C4;
    int r  = idx / C4;
    int j  = r % RES2; r /= RES2;
    int i  = r % RES2;
    int bb = r / RES2;

    const us4* v4 = (const us4*)v;
    const float4* w4 = (const float4*)w;
    float4 acc = make_float4(0.f, 0.f, 0.f, 0.f);
    #pragma unroll
    for (int dy = 0; dy < 3; ++dy) {
        int iy = 2 * i + dy;
        if (iy >= RES) continue;
        #pragma unroll
        for (int dx = 0; dx < 3; ++dx) {
            int ix = 2 * j + dx;
            if (ix >= RES) continue;
            us4 xu = v4[((size_t)(bb * RES + iy) * RES + ix) * C4 + c4];
            float4 wv = w4[(dy * 3 + dx) * C4 + c4];
            acc.x += bf2f(xu.x) * wv.x; acc.y += bf2f(xu.y) * wv.y;
            acc.z += bf2f(xu.z) * wv.z; acc.w += bf2f(xu.w) * wv.w;
        }
    }
    float4 bv = ((const float4*)b)[c4];
    float4 sv = ((const float4*)s)[c4];
    float4 hv = ((const float4*)sh)[c4];
    us4 o;
    o.x = f2bf((acc.x + bv.x) * sv.x + hv.x);
    o.y = f2bf((acc.y + bv.y) * sv.y + hv.y);
    o.z = f2bf((acc.z + bv.z) * sv.z + hv.z);
    o.w = f2bf((acc.w + bv.w) * sv.w + hv.w);
    ((us4*)out)[idx] = o;
}

// ---------------------------------------------------------------------------
// V -> PV B-fragment layout (the exact k-permuted gather the attn kernel's
// old in-loop repack did, done once offline):
// vfrag[bh][ti][fr=ns*2+pr][lane][j], us8 per lane, where element
//   j -> V[b][key = ti*64 + pr*32 + (j>>2)*16 + (lane>>4)*4 + (j&3)]
//              [d = ns*16 + (lane&15)]        (key clamped to 783)
// attn then loads vf with ONE global us8 per fragment: no LDS, no repack.
// ---------------------------------------------------------------------------
__global__ __launch_bounds__(256)
void vfrag_kernel(const u16* __restrict__ vbuf, u16* __restrict__ vf)
{
    __shared__ u16 tile[64][72];          // [key_local][d], 16B-aligned rows
    const int t  = threadIdx.x;
    const int b  = blockIdx.x;
    const int ti = blockIdx.y;
    const int h  = blockIdx.z;
    const int k0 = ti * 64;
    {
        int kr = t >> 2, cc = (t & 3) * 16;
        int key = k0 + kr; if (key > 783) key = 783;   // clamp: always valid data
        const u16* src = vbuf + ((size_t)b * NSEQ + key) * DHID + h * 64 + cc;
        us8 v0 = *(const us8*)src;
        us8 v1 = *(const us8*)(src + 8);
        *(us8*)&tile[kr][cc]     = v0;
        *(us8*)&tile[kr][cc + 8] = v1;
    }
    __syncthreads();
    {
        u16* dst = vf + (((size_t)(b * NHEAD + h) * 13 + ti) * 8) * 512;
        #pragma unroll
        for (int s0 = 0; s0 < 2; ++s0) {
            int s = t + s0 * 256;          // slot 0..511 = fr*64 + lane
            int lane = s & 63, fr = s >> 6;
            int ns = fr >> 1, pr = fr & 1;
            int col = lane & 15, quad = lane >> 4;
            us8 o;
            #pragma unroll
            for (int j = 0; j < 8; ++j)
                o[j] = tile[pr * 32 + (j >> 2) * 16 + quad * 4 + (j & 3)][ns * 16 + col];
            *(us8*)(dst + (size_t)s * 8) = o;
        }
    }
}

// ---------------------------------------------------------------------------
// MFMA flash attention, split-q x2 — LDS-free / barrier-free.
// blockIdx.x = (h*64 + b)*2 + par; 4 independent waves; wave w owns q-tiles
// {w + 4*(par*2+i)}. K ([bh][tok][16]) and V (vfrag, pre-permuted fragment
// layout) are loaded straight from global: K/biasC are L2-resident, vfrag is
// L3-resident. Zero __syncthreads -> waves free-run; phase-split per tile
// (QK+softmax for both i, then vf load, then both PVs) keeps kf and vf
// liveness disjoint -> VGPR <= 128 -> 4 blocks/CU resident.
// ---------------------------------------------------------------------------
__global__ __launch_bounds__(256, 4)
void attn_mfma_kernel(const u16* __restrict__ q, const u16* __restrict__ k,
                      const u16* __restrict__ vfrag, const float* __restrict__ biasC,
                      u16* __restrict__ io)
{
    const int t    = threadIdx.x;
    const int w    = t >> 6;
    const int lane = t & 63;
    const int col  = lane & 15;
    const int quad = lane >> 4;
    const int par = blockIdx.x & 1;
    const int bhx = blockIdx.x >> 1;
    const int h  = bhx >> 6;
    const int b  = bhx & 63;
    const int bh = b * NHEAD + h;

    // Q frags (q pre-scaled by 0.25), head-split layout
    short8_t qf[2];
    #pragma unroll
    for (int i = 0; i < 2; ++i) {
        int qt = w + 4 * (par * 2 + i);
        qf[i] = (short8_t)0;
        if (qt < 13 && quad < 2) {
            int qq = qt * 16 + col; if (qq > 195) qq = 195;
            qf[i] = *(const short8_t*)(q + ((size_t)bh * N2SEQ + qq) * 16 + quad * 8);
        }
    }

    f32x4 O[2][4];
    float m[2], l[2];
    #pragma unroll
    for (int i = 0; i < 2; ++i) {
        m[i] = -3e38f; l[i] = 0.f;
        #pragma unroll
        for (int ns = 0; ns < 4; ++ns) O[i][ns] = (f32x4)0.0f;
    }

    const u16* kb  = k + (size_t)bh * NSEQ * 16;
    const u16* vfb = vfrag + (size_t)bh * (13 * 4096);

    for (int ti = 0; ti < 13; ++ti) {
        const int t0 = ti * 64;

        // K fragments direct from global (L2): same bytes the old LDS stage held
        short8_t kf[4];
        #pragma unroll
        for (int ks = 0; ks < 4; ++ks) {
            kf[ks] = (short8_t)0;
            if (quad < 2) {
                int tok = t0 + ks * 16 + col; if (tok > 783) tok = 783;
                kf[ks] = *(const short8_t*)(kb + (size_t)tok * 16 + quad * 8);
            }
        }

        // Phase 1: QK^T + online softmax for both q-tiles (kf live, vf not)
        short8_t pf[2][2];
        float alpha[2];
        #pragma unroll
        for (int i = 0; i < 2; ++i) {
            int qt = w + 4 * (par * 2 + i);
            if (qt < 13) {
                const float* cb = biasC +
                    ((((size_t)h * 13 + ti) * 4) * 13 + qt) * 256 + lane * 4;
                f32x4 S[4];
                #pragma unroll
                for (int ks = 0; ks < 4; ++ks) {
                    f32x4 c = *(const f32x4*)(cb + (size_t)ks * (13 * 256));
                    S[ks] = __builtin_amdgcn_mfma_f32_16x16x32_bf16(kf[ks], qf[i], c, 0, 0, 0);
                }
                float mt = -3e38f;
                #pragma unroll
                for (int ks = 0; ks < 4; ++ks)
                    #pragma unroll
                    for (int r = 0; r < 4; ++r) mt = fmaxf(mt, S[ks][r]);
                mt = fmaxf(mt, __shfl_xor(mt, 16));
                mt = fmaxf(mt, __shfl_xor(mt, 32));
                float mnew = fmaxf(m[i], mt);
                alpha[i] = __expf(m[i] - mnew);
                m[i] = mnew;
                float s = 0.f;
                #pragma unroll
                for (int ks = 0; ks < 4; ++ks)
                    #pragma unroll
                    for (int r = 0; r < 4; ++r) {
                        float e = __expf(S[ks][r] - mnew);
                        S[ks][r] = e; s += e;
                    }
                s += __shfl_xor(s, 16);
                s += __shfl_xor(s, 32);
                l[i] = l[i] * alpha[i] + s;
                #pragma unroll
                for (int pr = 0; pr < 2; ++pr)
                    #pragma unroll
                    for (int j = 0; j < 8; ++j)
                        pf[i][pr][j] = (short)f2bf(S[2 * pr + (j >> 2)][j & 3]);
            }
        }

        // Phase 2: V fragments direct from global (kf dead now)
        short8_t vf[4][2];
        #pragma unroll
        for (int ns = 0; ns < 4; ++ns)
            #pragma unroll
            for (int pr = 0; pr < 2; ++pr)
                vf[ns][pr] = *(const short8_t*)
                    (vfb + ((size_t)(ti * 8 + ns * 2 + pr)) * 512 + lane * 8);

        // Phase 3: rescale + PV for both q-tiles
        #pragma unroll
        for (int i = 0; i < 2; ++i) {
            int qt = w + 4 * (par * 2 + i);
            if (qt < 13) {
                float ar[4];
                #pragma unroll
                for (int r = 0; r < 4; ++r) ar[r] = __shfl(alpha[i], quad * 4 + r);
                #pragma unroll
                for (int ns = 0; ns < 4; ++ns)
                    #pragma unroll
                    for (int r = 0; r < 4; ++r) O[i][ns][r] *= ar[r];
                #pragma unroll
                for (int ns = 0; ns < 4; ++ns)
                    #pragma unroll
                    for (int pr = 0; pr < 2; ++pr)
                        O[i][ns] = __builtin_amdgcn_mfma_f32_16x16x32_bf16(
                            pf[i][pr], vf[ns][pr], O[i][ns], 0, 0, 0);
            }
        }
    }

    // epilogue: O/l + v_local (RMW io, flat [b][q][512])
    #pragma unroll
    for (int i = 0; i < 2; ++i) {
        int qt = w + 4 * (par * 2 + i);
        if (qt < 13) {
            float linv = 1.0f / l[i];
            float lr[4];
            #pragma unroll
            for (int r = 0; r < 4; ++r) lr[r] = __shfl(linv, quad * 4 + r);
            #pragma unroll
            for (int ns = 0; ns < 4; ++ns)
                #pragma unroll
                for (int r = 0; r < 4; ++r) {
                    int q2 = qt * 16 + quad * 4 + r;
                    if (q2 < N2SEQ) {
                        size_t a = ((size_t)(b * N2SEQ + q2) * DHID) + h * 64 + ns * 16 + col;
                        io[a] = f2bf(O[i][ns][r] * lr[r] + bf2f(io[a]));
                    }
                }
        }
    }
}

// ---------------------------------------------------------------------------
extern "C" void kernel_launch(void* const* d_in, const int* in_sizes, int n_in,
                              void* d_out, int out_size, void* d_ws, size_t ws_size,
                              hipStream_t stream)
{
    const float* x          = (const float*)d_in[0];
    const float* q_local_w  = (const float*)d_in[1];
    const float* q_local_b  = (const float*)d_in[2];
    const float* q_proj_w   = (const float*)d_in[3];
    const float* q_proj_b   = (const float*)d_in[4];
    const float* q_bn_s     = (const float*)d_in[5];
    const float* q_bn_b     = (const float*)d_in[6];
    const float* k_w        = (const float*)d_in[7];
    const float* k_b        = (const float*)d_in[8];
    const float* k_bn_s     = (const float*)d_in[9];
    const float* k_bn_b     = (const float*)d_in[10];
    const float* v_w        = (const float*)d_in[11];
    const float* v_b        = (const float*)d_in[12];
    const float* v_bn_s     = (const float*)d_in[13];
    const float* v_bn_b     = (const float*)d_in[14];
    const float* vloc_w     = (const float*)d_in[15];
    const float* vloc_b     = (const float*)d_in[16];
    const float* vloc_bn_s  = (const float*)d_in[17];
    const float* vloc_bn_b  = (const float*)d_in[18];
    const float* proj_w     = (const float*)d_in[19];
    const float* proj_b     = (const float*)d_in[20];
    const float* proj_bn_s  = (const float*)d_in[21];
    const float* proj_bn_b  = (const float*)d_in[22];
    const float* attn_bias  = (const float*)d_in[23];
    float* out = (float*)d_out;

    const int M1 = BATCH * NSEQ;    // 50176
    const int M2 = BATCH * N2SEQ;   // 12544

    // ---- workspace (bytes), ~138 MB ----
    // Region A time-shared: qin_bf (phases 1-3) then vfrag (after q GEMM).
    char* p = (char*)d_ws;
    u16* qin_bf = (u16*)p;                         //  9,633,792
    u16* vfrag  = (u16*)p;                         // 54,525,952 (overlays)
    size_t off = 54525952;
    u16* kvwt = (u16*)(p + off);  off += 640 * 384 * 2;       // 491,520
    u16* qwt  = (u16*)(p + off);  off += 128 * 384 * 2;       //  98,304
    u16* pwt  = (u16*)(p + off);  off += 768 * 512 * 2;       // 786,432
    float* kv_eps = (float*)(p + off); off += 1920 * 4;
    float* qsb    = (float*)(p + off); off += 256 * 4;
    u16* kbuf = (u16*)(p + off);    off += (size_t)M1 * 128 * 2;
    u16* vbuf = (u16*)(p + off);    off += (size_t)M1 * DHID * 2;
    u16* qbuf = (u16*)(p + off);    off += (size_t)M2 * 128 * 2;
    u16* vloc_bf = (u16*)(p + off); off += (size_t)M2 * DHID * 2;
    float* biasC = (float*)(p + off);

    // 1. prep (weights/eps) + biasC
    prep_kernel<<<dim3((PREP_N + 255) / 256), 256, 0, stream>>>(
        k_w, v_w, q_proj_w, proj_w, k_b, v_b, k_bn_s, v_bn_s, k_bn_b, v_bn_b,
        q_bn_s, q_bn_b, kvwt, qwt, pwt, kv_eps, qsb);
    {
        int items = NHEAD * 13 * 4 * 13 * 64;
        biasC_kernel<<<dim3((items + 255) / 256), 256, 0, stream>>>(attn_bias, biasC);
    }
    // 2. q_in (bf16)
    {
        int items = M2 * (CIN / 4);
        qin_kernel<<<dim3((items + 255) / 256), 256, 0, stream>>>(x, q_local_w, q_local_b, qin_bf);
    }
    // 3. fused k+v GEMM (fp32 A staged->bf16), then q GEMM
    gemm_mfma_kernel<3, 1><<<dim3(M1 / TM, 640 / TN), 256, 0, stream>>>(
        x, kvwt, kv_eps, kv_eps + 640, kv_eps + 1280, kbuf, vbuf, M1, 640, CIN, NSEQ);
    gemm_mfma_kernel<2, 0><<<dim3(M2 / TM, 128 / TN), 256, 0, stream>>>(
        qin_bf, qwt, q_proj_b, qsb, qsb + 128, qbuf, nullptr, M2, 128, CIN, N2SEQ);

    // 4. V -> fragment layout (overwrites region A — qin_bf dead)
    vfrag_kernel<<<dim3(BATCH, 13, NHEAD), 256, 0, stream>>>(vbuf, vfrag);

    // 5. v_local (bf16 — attention adds into it)
    {
        int items = M2 * (DHID / 4);
        vloc_kernel<<<dim3((items + 255) / 256), 256, 0, stream>>>(
            vbuf, vloc_w, vloc_b, vloc_bn_s, vloc_bn_b, vloc_bf);
    }
    // 6. MFMA flash attention, LDS-free / barrier-free
    attn_mfma_kernel<<<dim3(NHEAD * BATCH * 2), 256, 0, stream>>>(
        qbuf, kbuf, vfrag, biasC, vloc_bf);

    // 7. proj GEMM (fp32 out)
    gemm_mfma_kernel<0, 0><<<dim3(M2 / TM, 768 / TN), 256, 0, stream>>>(
        vloc_bf, pwt, proj_b, proj_bn_s, proj_bn_b, out, nullptr, M2, 768, DHID, 0);
}